// Round 15
// baseline (413.622 us; speedup 1.0000x reference)
//
#include <hip/hip_runtime.h>
#include <hip/hip_bf16.h>
#include <math.h>

typedef __hip_bfloat16 BF;
typedef __bf16 bf16x8 __attribute__((ext_vector_type(8)));
typedef float f32x4 __attribute__((ext_vector_type(4)));

struct alignas(8) BF4 { BF v[4]; };
struct alignas(16) BF8 { BF v[8]; };

static __device__ __forceinline__ float b2f(BF x) { return __bfloat162float(x); }
static __device__ __forceinline__ BF f2b(float x) { return __float2bfloat16(x); }

// async global->LDS, 16B per lane; LDS dest = wave-uniform base (+lane*16 implicit)
static __device__ __forceinline__ void gld_lds16(const void* g, void* l) {
  __builtin_amdgcn_global_load_lds(
      (const __attribute__((address_space(1))) unsigned int*)g,
      (__attribute__((address_space(3))) unsigned int*)l, 16, 0, 0);
}

// ---------------------------------------------------------------------------
// f32 -> bf16 convert, 4 elements/thread, grid-stride
// ---------------------------------------------------------------------------
__global__ void __launch_bounds__(256) cvt_kernel(
    const float* __restrict__ in, BF* __restrict__ out, int n4) {
  for (int i = blockIdx.x * 256 + threadIdx.x; i < n4; i += gridDim.x * 256) {
    float4 v = ((const float4*)in)[i];
    BF4 o;
    o.v[0] = f2b(v.x); o.v[1] = f2b(v.y); o.v[2] = f2b(v.z); o.v[3] = f2b(v.w);
    ((BF4*)out)[i] = o;
  }
}

// concat bk||bv -> bkv (f32), 2 blocks x 256
__global__ void __launch_bounds__(256) bkv_kernel(
    const float* __restrict__ bk, const float* __restrict__ bv,
    float* __restrict__ bkv) {
  int i = blockIdx.x * 256 + threadIdx.x;
  bkv[i] = (i < 256) ? bk[i] : bv[i - 256];
}

enum { EPI_NONE = 0, EPI_RES = 1, EPI_GELU = 2 };

// ---------------------------------------------------------------------------
// gemm_tn: R11 form (256 threads, 128x128, LDS-coalesced epilogue, (256,4)).
// Used ONLY for MLP2 (grid 512 -> 4 blocks/CU; wide tile would grid-starve).
// ---------------------------------------------------------------------------
template <int EPI, typename AT, typename RT, typename CT>
__global__ void __launch_bounds__(256, 4) gemm_tn(
    const AT* __restrict__ A, const BF* __restrict__ Bw,
    const float* __restrict__ bias, const RT* __restrict__ Res,
    CT* __restrict__ C, int M, int N, int K) {
  constexpr bool F32A = __is_same(AT, float);
  alignas(16) __shared__ BF smem[128 * 136];     // staging (32KB) / C-tile
  BF* As = smem;                                  // [8][128][8]
  BF* Bs = smem + 8192;                           // [8][128][8]
  BF* Cb = smem;                                  // [128][136] padded C tile
  const int ntiles = N >> 7;
  const int cpx = gridDim.x >> 3;
  const int bid = blockIdx.x;
  const int swz = (bid & 7) * cpx + (bid >> 3);   // XCD-chunked, bijective
  const int mt = swz / ntiles, nt = swz % ntiles;
  const int row0 = mt << 7, col0 = nt << 7;
  const int t = threadIdx.x;
  const int wave = t >> 6, lane = t & 63;
  const int wr = wave >> 1, wc = wave & 1;
  const int sm = t & 127;
  const int skc = t >> 7;
  f32x4 acc[4][4] = {};
  const int NT = K >> 6;
  float4 ar[4][2];

  auto stageB = [&](int kt) {
#pragma unroll
    for (int i = 0; i < 4; ++i) {
      const int kc = i * 2 + skc;
      gld_lds16(Bw + (size_t)(col0 + sm) * K + kt * 64 + kc * 8,
                Bs + (size_t)(i * 256 + wave * 64) * 8);
    }
  };
  auto loadA = [&](int kt) {
    if constexpr (F32A) {
#pragma unroll
      for (int i = 0; i < 4; ++i) {
        const int kc = i * 2 + skc;
        const float* src = A + (size_t)(row0 + sm) * K + kt * 64 + kc * 8;
        ar[i][0] = ((const float4*)src)[0];
        ar[i][1] = ((const float4*)src)[1];
      }
    }
  };
  auto writeA = [&]() {
    if constexpr (F32A) {
#pragma unroll
      for (int i = 0; i < 4; ++i) {
        const int kc = i * 2 + skc;
        BF tmp[8];
        tmp[0] = f2b(ar[i][0].x); tmp[1] = f2b(ar[i][0].y);
        tmp[2] = f2b(ar[i][0].z); tmp[3] = f2b(ar[i][0].w);
        tmp[4] = f2b(ar[i][1].x); tmp[5] = f2b(ar[i][1].y);
        tmp[6] = f2b(ar[i][1].z); tmp[7] = f2b(ar[i][1].w);
        *(bf16x8*)(As + (kc * 128 + sm) * 8) = *(bf16x8*)tmp;
      }
    }
  };
  auto stageA_bf = [&](int kt) {
    if constexpr (!F32A) {
#pragma unroll
      for (int i = 0; i < 4; ++i) {
        const int kc = i * 2 + skc;
        gld_lds16((const BF*)A + (size_t)(row0 + sm) * K + kt * 64 + kc * 8,
                  As + (size_t)(i * 256 + wave * 64) * 8);
      }
    }
  };
  auto compute = [&]() {
#pragma unroll
    for (int kk = 0; kk < 2; ++kk) {
      const int chunk = kk * 4 + (lane >> 4);
      const int rl = lane & 15;
      bf16x8 af[4], bfr[4];
#pragma unroll
      for (int mi = 0; mi < 4; ++mi)
        af[mi] = *(const bf16x8*)(As + (chunk * 128 + wr * 64 + mi * 16 + rl) * 8);
#pragma unroll
      for (int ni = 0; ni < 4; ++ni)
        bfr[ni] = *(const bf16x8*)(Bs + (chunk * 128 + wc * 64 + ni * 16 + rl) * 8);
#pragma unroll
      for (int mi = 0; mi < 4; ++mi)
#pragma unroll
        for (int ni = 0; ni < 4; ++ni)
          acc[mi][ni] = __builtin_amdgcn_mfma_f32_16x16x32_bf16(
              af[mi], bfr[ni], acc[mi][ni], 0, 0, 0);
    }
  };

  loadA(0);
  for (int kt = 0; kt < NT; ++kt) {
    writeA();
    stageA_bf(kt);
    stageB(kt);
    if (kt + 1 < NT) loadA(kt + 1);
    __syncthreads();
    compute();
    __syncthreads();
  }

  // phase 1: epi(acc+bias) -> padded LDS tile (D layout m89-verified)
  {
    const int rl = lane & 15, rg = lane >> 4;
#pragma unroll
    for (int mi = 0; mi < 4; ++mi)
#pragma unroll
      for (int ni = 0; ni < 4; ++ni) {
        const int col = wc * 64 + ni * 16 + rl;
        const float bcol = bias[col0 + col];
#pragma unroll
        for (int r = 0; r < 4; ++r) {
          const int row = wr * 64 + mi * 16 + rg * 4 + r;
          float v = acc[mi][ni][r] + bcol;
          if constexpr (EPI == EPI_GELU)
            v = 0.5f * v * (1.0f + erff(v * 0.70710678118654752f));
          Cb[row * 136 + col] = f2b(v);
        }
      }
  }
  __syncthreads();
  // phase 2: coalesced out (wave-instr = 4 complete 256B rows)
#pragma unroll
  for (int j = 0; j < 8; ++j) {
    const int row = wave * 32 + j * 4 + (lane >> 4);
    const int colc = (lane & 15) * 8;
    bf16x8 vb = *(const bf16x8*)(Cb + row * 136 + colc);
    const size_t goff = (size_t)(row0 + row) * N + col0 + colc;
    float o[8];
#pragma unroll
    for (int h = 0; h < 8; ++h) o[h] = (float)vb[h];
    if constexpr (EPI == EPI_RES) {
      if constexpr (__is_same(RT, float)) {
        float4 r0 = *(const float4*)(Res + goff);
        float4 r1 = *(const float4*)(Res + goff + 4);
        o[0] += r0.x; o[1] += r0.y; o[2] += r0.z; o[3] += r0.w;
        o[4] += r1.x; o[5] += r1.y; o[6] += r1.z; o[7] += r1.w;
      } else {
        BF8 rb = *(const BF8*)(Res + goff);
#pragma unroll
        for (int h = 0; h < 8; ++h) o[h] += b2f(rb.v[h]);
      }
    }
    if constexpr (__is_same(CT, float)) {
      float4 s0 = {o[0], o[1], o[2], o[3]};
      float4 s1 = {o[4], o[5], o[6], o[7]};
      *(float4*)(C + goff) = s0;
      *(float4*)(C + goff + 4) = s1;
    } else {
      BF8 ob;
#pragma unroll
      for (int h = 0; h < 8; ++h) ob.v[h] = f2b(o[h]);
      *(BF8*)(C + goff) = ob;
    }
  }
}

// ---------------------------------------------------------------------------
// gemm_tn_w: R12/R13-measured form. 512 threads, 128x256 tile (halves A
// re-reads), 8 waves (2x4), single 48KB LDS, m97 loop. Used for KV, MLP1,
// and now Wo (ntiles=1: A read once; grid 512 -> 2 blocks/CU).
// ---------------------------------------------------------------------------
template <int EPI, typename AT, typename RT, typename CT>
__global__ void __launch_bounds__(512, 4) gemm_tn_w(
    const AT* __restrict__ A, const BF* __restrict__ Bw,
    const float* __restrict__ bias, const RT* __restrict__ Res,
    CT* __restrict__ C, int M, int N, int K) {
  constexpr bool F32A = __is_same(AT, float);
  alignas(16) __shared__ BF As[8][128][8];   // 16KB
  alignas(16) __shared__ BF Bs[8][256][8];   // 32KB
  const int ntiles = N >> 8;
  const int cpx = gridDim.x >> 3;
  const int bid = blockIdx.x;
  const int swz = (bid & 7) * cpx + (bid >> 3);
  const int mt = swz / ntiles, nt = swz % ntiles;
  const int row0 = mt << 7, col0 = nt << 8;
  const int t = threadIdx.x;
  const int wave = t >> 6, lane = t & 63;
  const int wr = wave >> 2, wc = wave & 3;        // 2x4 wave grid
  const int sm = t & 127;
  const int skc = t >> 7;                         // 0..3
  f32x4 acc[4][4] = {};
  const int NT = K >> 6;
  float4 ar[2][2];

  auto stageB = [&](int kt) {
#pragma unroll
    for (int i = 0; i < 4; ++i) {
      const int c = i * 512 + t;
      const int kc = c >> 8, n = c & 255;
      gld_lds16(Bw + (size_t)(col0 + n) * K + kt * 64 + kc * 8,
                &Bs[0][0][0] + (size_t)(i * 512 + wave * 64) * 8);
    }
  };
  auto stageA_bf = [&](int kt) {
    if constexpr (!F32A) {
#pragma unroll
      for (int i = 0; i < 2; ++i) {
        const int c = i * 512 + t;
        const int kc = c >> 7, m = c & 127;
        gld_lds16((const BF*)A + (size_t)(row0 + m) * K + kt * 64 + kc * 8,
                  &As[0][0][0] + (size_t)(i * 512 + wave * 64) * 8);
      }
    }
  };
  auto loadA = [&](int kt) {
    if constexpr (F32A) {
#pragma unroll
      for (int i = 0; i < 2; ++i) {
        const int kc = i * 4 + skc;
        const float* src = A + (size_t)(row0 + sm) * K + kt * 64 + kc * 8;
        ar[i][0] = ((const float4*)src)[0];
        ar[i][1] = ((const float4*)src)[1];
      }
    }
  };
  auto writeA = [&]() {
    if constexpr (F32A) {
#pragma unroll
      for (int i = 0; i < 2; ++i) {
        const int kc = i * 4 + skc;
        BF tmp[8];
        tmp[0] = f2b(ar[i][0].x); tmp[1] = f2b(ar[i][0].y);
        tmp[2] = f2b(ar[i][0].z); tmp[3] = f2b(ar[i][0].w);
        tmp[4] = f2b(ar[i][1].x); tmp[5] = f2b(ar[i][1].y);
        tmp[6] = f2b(ar[i][1].z); tmp[7] = f2b(ar[i][1].w);
        *(bf16x8*)(&As[kc][sm][0]) = *(bf16x8*)tmp;
      }
    }
  };
  auto compute = [&]() {
#pragma unroll
    for (int kk = 0; kk < 2; ++kk) {
      const int chunk = kk * 4 + (lane >> 4);
      const int rl = lane & 15;
      bf16x8 af[4], bfr[4];
#pragma unroll
      for (int mi = 0; mi < 4; ++mi)
        af[mi] = *(const bf16x8*)(&As[chunk][wr * 64 + mi * 16 + rl][0]);
#pragma unroll
      for (int ni = 0; ni < 4; ++ni)
        bfr[ni] = *(const bf16x8*)(&Bs[chunk][wc * 64 + ni * 16 + rl][0]);
#pragma unroll
      for (int mi = 0; mi < 4; ++mi)
#pragma unroll
        for (int ni = 0; ni < 4; ++ni)
          acc[mi][ni] = __builtin_amdgcn_mfma_f32_16x16x32_bf16(
              af[mi], bfr[ni], acc[mi][ni], 0, 0, 0);
    }
  };

  loadA(0);
  for (int kt = 0; kt < NT; ++kt) {
    writeA();
    stageA_bf(kt);
    stageB(kt);
    if (kt + 1 < NT) loadA(kt + 1);
    __syncthreads();
    compute();
    __syncthreads();
  }

  const int rl = lane & 15, rg = lane >> 4;
#pragma unroll
  for (int mi = 0; mi < 4; ++mi) {
#pragma unroll
    for (int ni = 0; ni < 4; ++ni) {
      const int col = col0 + wc * 64 + ni * 16 + rl;
      const float bcol = bias[col];
#pragma unroll
      for (int r = 0; r < 4; ++r) {
        const int row = row0 + wr * 64 + mi * 16 + rg * 4 + r;
        float v = acc[mi][ni][r] + bcol;
        if constexpr (EPI == EPI_GELU)
          v = 0.5f * v * (1.0f + erff(v * 0.70710678118654752f));
        if constexpr (EPI == EPI_RES) {
          if constexpr (__is_same(RT, float))
            v += Res[(size_t)row * N + col];
          else
            v += b2f(Res[(size_t)row * N + col]);
        }
        if constexpr (__is_same(CT, float))
          C[(size_t)row * N + col] = v;
        else
          C[(size_t)row * N + col] = f2b(v);
      }
    }
  }
}

// ---------------------------------------------------------------------------
// Q-projection GEMM (R12-verified 512-thread form): tile 128x256 (ntiles=1:
// s read ONCE), attention-layout scatter epilogue (pre-scaled):
//   Qa[b][wi][nh][qi][hd] = (s @ Wq^T + bq)[b, l, c] * SCALE
//   l = nh*2048 + hd*64 + qi*16 + hi, wi = hi*256 + c.
// ---------------------------------------------------------------------------
__global__ void __launch_bounds__(512, 4) gemm_q(
    const float* __restrict__ A, const BF* __restrict__ Bw,
    const float* __restrict__ bias, BF* __restrict__ Qa) {
  constexpr int K = 256;
  alignas(16) __shared__ BF As[8][128][8];
  alignas(16) __shared__ BF Bs[8][256][8];
  const int cpx = gridDim.x >> 3;
  const int bid = blockIdx.x;
  const int mt = (bid & 7) * cpx + (bid >> 3);
  const int hp = mt & 3, qi = (mt >> 2) & 3, nh = (mt >> 4) & 7, bb = mt >> 7;
  const int t = threadIdx.x;
  const int wave = t >> 6, lane = t & 63;
  const int wr = wave >> 2, wc = wave & 3;
  const int sm = t & 127;
  const int skc = t >> 7;
  const size_t grow = (size_t)bb * 16384 + nh * 2048 + (size_t)(sm & 31) * 64 +
                      qi * 16 + hp * 4 + (sm >> 5);
  f32x4 acc[4][4] = {};
  float4 ar[2][2];

  auto stageB = [&](int kt) {
#pragma unroll
    for (int i = 0; i < 4; ++i) {
      const int c = i * 512 + t;
      const int kc = c >> 8, n = c & 255;
      gld_lds16(Bw + (size_t)n * K + kt * 64 + kc * 8,
                &Bs[0][0][0] + (size_t)(i * 512 + wave * 64) * 8);
    }
  };
  auto loadA = [&](int kt) {
#pragma unroll
    for (int i = 0; i < 2; ++i) {
      const int kc = i * 4 + skc;
      const float* src = A + grow * K + kt * 64 + kc * 8;
      ar[i][0] = ((const float4*)src)[0];
      ar[i][1] = ((const float4*)src)[1];
    }
  };
  auto writeA = [&]() {
#pragma unroll
    for (int i = 0; i < 2; ++i) {
      const int kc = i * 4 + skc;
      BF tmp[8];
      tmp[0] = f2b(ar[i][0].x); tmp[1] = f2b(ar[i][0].y);
      tmp[2] = f2b(ar[i][0].z); tmp[3] = f2b(ar[i][0].w);
      tmp[4] = f2b(ar[i][1].x); tmp[5] = f2b(ar[i][1].y);
      tmp[6] = f2b(ar[i][1].z); tmp[7] = f2b(ar[i][1].w);
      *(bf16x8*)(&As[kc][sm][0]) = *(bf16x8*)tmp;
    }
  };
  auto compute = [&]() {
#pragma unroll
    for (int kk = 0; kk < 2; ++kk) {
      const int chunk = kk * 4 + (lane >> 4);
      const int rl = lane & 15;
      bf16x8 af[4], bfr[4];
#pragma unroll
      for (int mi = 0; mi < 4; ++mi)
        af[mi] = *(const bf16x8*)(&As[chunk][wr * 64 + mi * 16 + rl][0]);
#pragma unroll
      for (int ni = 0; ni < 4; ++ni)
        bfr[ni] = *(const bf16x8*)(&Bs[chunk][wc * 64 + ni * 16 + rl][0]);
#pragma unroll
      for (int mi = 0; mi < 4; ++mi)
#pragma unroll
        for (int ni = 0; ni < 4; ++ni)
          acc[mi][ni] = __builtin_amdgcn_mfma_f32_16x16x32_bf16(
              af[mi], bfr[ni], acc[mi][ni], 0, 0, 0);
    }
  };

  loadA(0);
  for (int kt = 0; kt < 4; ++kt) {
    writeA();
    stageB(kt);
    if (kt + 1 < 4) loadA(kt + 1);
    __syncthreads();
    compute();
    __syncthreads();
  }

  const int rl = lane & 15, rg = lane >> 4;
  const float SCALE = 0.17677669529663689f;  // 32^-0.5
#pragma unroll
  for (int mi = 0; mi < 4; ++mi) {
#pragma unroll
    for (int ni = 0; ni < 4; ++ni) {
      const int col = wc * 64 + ni * 16 + rl;      // [0,256)
      const float bcol = bias[col];
      const int i0 = wr * 64 + mi * 16 + rg * 4;   // [0,128)
      const int hd = i0 & 31, hil = i0 >> 5;
      const int wi = (hp * 4 + hil) * 256 + col;
      BF4 pk;
#pragma unroll
      for (int r = 0; r < 4; ++r)
        pk.v[r] = f2b((acc[mi][ni][r] + bcol) * SCALE);
      *(BF4*)(Qa + ((((size_t)bb * 4096 + wi) * 8 + nh) * 128 + qi * 32 + hd)) = pk;
    }
  }
}

// ---------------------------------------------------------------------------
// Windowed attention v4 (R10/R11-verified): inline rel-bias, no LDS, no QK
// shuffles. 16-lane group per (w,nh), lane = qi*4+kj.
// ---------------------------------------------------------------------------
__global__ void __launch_bounds__(256) attn_kernel(
    const BF* __restrict__ Qa, const BF* __restrict__ KV,
    const float* __restrict__ s_pos, const float* __restrict__ x_pos,
    const float* __restrict__ pw1, const float* __restrict__ pb1,
    const float* __restrict__ bn_g, const float* __restrict__ bn_b,
    const float* __restrict__ bn_m, const float* __restrict__ bn_v,
    const float* __restrict__ pw2, const float* __restrict__ pb2,
    BF* __restrict__ O) {
  const int t = threadIdx.x;
  const int g = t >> 4, l16 = t & 15;
  const int qi = l16 >> 2, kj = l16 & 3;
  const int w = (blockIdx.x << 1) | (g >> 3);
  const int nh = g & 7;
  const int b = w >> 12, wi = w & 4095;

  const uint4* qp = (const uint4*)(Qa + ((((size_t)b * 4096 + wi) * 8 + nh) * 128 + qi * 32));
  uint4 qv[4] = {qp[0], qp[1], qp[2], qp[3]};
  const uint4* kp = (const uint4*)(KV + ((size_t)b * 16384 + kj * 4096 + wi) * 512 + nh * 32);
  uint4 kv[4] = {kp[0], kp[1], kp[2], kp[3]};
  const BF* vbase = KV + (size_t)b * 16384 * 512 + 256 + nh * 32 + kj * 8;
  uint4 vv[4];
#pragma unroll
  for (int d = 0; d < 4; ++d)
    vv[d] = *(const uint4*)(vbase + ((size_t)((kj ^ d) * 4096 + wi)) * 512);

  const size_t sprow = ((size_t)(b * 2 + (qi & 1)) * 4096 + wi) * 4;
  const float r0 = s_pos[sprow + (qi >> 1)] -
                   x_pos[((size_t)b * 16384 + kj * 4096 + wi) * 2 + 0];
  const float r1 = s_pos[sprow + 2 + (qi >> 1)] -
                   x_pos[((size_t)b * 16384 + kj * 4096 + wi) * 2 + 1];
  float bias_l = pb2[nh];
#pragma unroll
  for (int o = 0; o < 16; ++o) {
    float tv = pw1[o * 2 + 0] * r0 + pw1[o * 2 + 1] * r1 + pb1[o];
    const float sc = bn_g[o] / sqrtf(bn_v[o] + 1e-5f);
    tv = (tv - bn_m[o]) * sc + bn_b[o];
    bias_l += pw2[nh * 16 + o] * fmaxf(tv, 0.0f);
  }

  float accs[4] = {0.f, 0.f, 0.f, 0.f};
#pragma unroll
  for (int j = 0; j < 4; ++j) {
#pragma unroll
    for (int e = 0; e < 4; ++e) {
      unsigned qe = ((const unsigned*)&qv[j])[e];
      unsigned ke = ((const unsigned*)&kv[j])[e];
      float ql = __uint_as_float(qe << 16);
      float qh = __uint_as_float(qe & 0xffff0000u);
      float kl = __uint_as_float(ke << 16);
      float kh = __uint_as_float(ke & 0xffff0000u);
      accs[e] = fmaf(ql, kl, accs[e]);
      accs[e] = fmaf(qh, kh, accs[e]);
    }
  }
  const float score = accs[0] + accs[1] + accs[2] + accs[3] + bias_l;

  float mx = fmaxf(score, __shfl_xor(score, 1));
  mx = fmaxf(mx, __shfl_xor(mx, 2));
  float e = __expf(score - mx);
  float sm = e + __shfl_xor(e, 1);
  sm += __shfl_xor(sm, 2);
  float p = e / sm;
  float pd[4];
  pd[0] = p;
  pd[1] = __shfl_xor(p, 1);
  pd[2] = __shfl_xor(p, 2);
  pd[3] = __shfl_xor(pd[1], 2);

  float o8[8] = {0.f, 0.f, 0.f, 0.f, 0.f, 0.f, 0.f, 0.f};
#pragma unroll
  for (int d = 0; d < 4; ++d) {
#pragma unroll
    for (int e2 = 0; e2 < 4; ++e2) {
      unsigned ve = ((const unsigned*)&vv[d])[e2];
      o8[e2 * 2 + 0] = fmaf(pd[d], __uint_as_float(ve << 16), o8[e2 * 2 + 0]);
      o8[e2 * 2 + 1] = fmaf(pd[d], __uint_as_float(ve & 0xffff0000u), o8[e2 * 2 + 1]);
    }
  }
  BF8 ob;
#pragma unroll
  for (int h = 0; h < 8; ++h) ob.v[h] = f2b(o8[h]);
  *(BF8*)(O + ((size_t)b * 16384 + qi * 4096 + wi) * 256 + nh * 32 + kj * 8) = ob;
}

// ---------------------------------------------------------------------------
// LayerNorm over C=256: one 64-lane wave per row, 4 bf16 per lane.
// ---------------------------------------------------------------------------
__global__ void __launch_bounds__(256) ln_kernel(
    const BF* __restrict__ S1, const float* __restrict__ g,
    const float* __restrict__ be, BF* __restrict__ Nout) {
  const int wave = threadIdx.x >> 6, lane = threadIdx.x & 63;
  const size_t row = (size_t)blockIdx.x * 4 + wave;
  BF4 d = *(const BF4*)(S1 + row * 256 + lane * 4);
  float x[4] = {b2f(d.v[0]), b2f(d.v[1]), b2f(d.v[2]), b2f(d.v[3])};
  float s = x[0] + x[1] + x[2] + x[3];
  float sq = x[0] * x[0] + x[1] * x[1] + x[2] * x[2] + x[3] * x[3];
#pragma unroll
  for (int m = 1; m <= 32; m <<= 1) {
    s += __shfl_xor(s, m);
    sq += __shfl_xor(sq, m);
  }
  const float mean = s * 0.00390625f;
  const float var = sq * 0.00390625f - mean * mean;
  const float rstd = 1.0f / sqrtf(var + 1e-5f);
  BF4 o;
#pragma unroll
  for (int jj = 0; jj < 4; ++jj) {
    float nv = (x[jj] - mean) * rstd * g[lane * 4 + jj] + be[lane * 4 + jj];
    o.v[jj] = f2b(nv);
  }
  *(BF4*)(Nout + row * 256 + lane * 4) = o;
}

// ---------------------------------------------------------------------------
// ws layout (bytes): unchanged from R11-R13.
//   [8388608,    41943040)  Qa bf16 -> LN out after attn
//   [41943040,  109051904)  KV512 bf16 -> H2 after attn
//   [109051904, 142606336)  S1 bf16
//   [142606336, ~144.2MB)   bf16 weights Wq,Wo,Wkv(stacked),mw1,mw2; bkv f32
// d_out doubles as bf16 attn-output staging. 16 dispatches.
// ---------------------------------------------------------------------------
extern "C" void kernel_launch(void* const* d_in, const int* in_sizes, int n_in,
                              void* d_out, int out_size, void* d_ws, size_t ws_size,
                              hipStream_t stream) {
  const float* s     = (const float*)d_in[0];
  const float* x     = (const float*)d_in[1];
  const float* s_pos = (const float*)d_in[2];
  const float* x_pos = (const float*)d_in[3];
  const float* Wq = (const float*)d_in[4];  const float* bq = (const float*)d_in[5];
  const float* Wk = (const float*)d_in[6];  const float* bk = (const float*)d_in[7];
  const float* Wv = (const float*)d_in[8];  const float* bv = (const float*)d_in[9];
  const float* Wo = (const float*)d_in[10]; const float* bo = (const float*)d_in[11];
  const float* pw1 = (const float*)d_in[12]; const float* pb1 = (const float*)d_in[13];
  const float* bn_g = (const float*)d_in[14]; const float* bn_b = (const float*)d_in[15];
  const float* bn_m = (const float*)d_in[16]; const float* bn_v = (const float*)d_in[17];
  const float* pw2 = (const float*)d_in[18]; const float* pb2 = (const float*)d_in[19];
  const float* ln_g = (const float*)d_in[20]; const float* ln_b = (const float*)d_in[21];
  const float* mw1 = (const float*)d_in[22]; const float* mb1 = (const float*)d_in[23];
  const float* mw2 = (const float*)d_in[24]; const float* mb2 = (const float*)d_in[25];

  char* ws = (char*)d_ws;
  BF* Qa   = (BF*)(ws + 8388608);
  BF* KVw  = (BF*)(ws + 41943040);
  BF* S1   = (BF*)(ws + 109051904);
  BF* Wq_bf  = (BF*)(ws + 142606336);
  BF* Wo_bf  = (BF*)(ws + 142737408);
  BF* Wkv_bf = (BF*)(ws + 142868480);
  BF* mw1_bf = (BF*)(ws + 143130624);
  BF* mw2_bf = (BF*)(ws + 143654912);
  float* bkv = (float*)(ws + 144179200);
  BF* Nw = Qa;            // LN output reuses Qa region (free after attn)
  BF* H2 = KVw;           // MLP hidden reuses KV region (free after attn)
  BF* ObBF = (BF*)d_out;  // attn output staged bf16 inside d_out
  float* Of = (float*)d_out;

  cvt_kernel<<<64, 256, 0, stream>>>(Wq, Wq_bf, 16384);
  cvt_kernel<<<64, 256, 0, stream>>>(Wo, Wo_bf, 16384);
  cvt_kernel<<<64, 256, 0, stream>>>(Wk, Wkv_bf, 16384);
  cvt_kernel<<<64, 256, 0, stream>>>(Wv, Wkv_bf + 65536, 16384);
  cvt_kernel<<<256, 256, 0, stream>>>(mw1, mw1_bf, 65536);
  cvt_kernel<<<256, 256, 0, stream>>>(mw2, mw2_bf, 65536);
  bkv_kernel<<<2, 256, 0, stream>>>(bk, bv, bkv);

  gemm_q<<<512, 512, 0, stream>>>(s, Wq_bf, bq, Qa);
  gemm_tn_w<EPI_NONE, float, float, BF><<<1024, 512, 0, stream>>>(
      x, Wkv_bf, bkv, nullptr, KVw, 65536, 512, 256);
  attn_kernel<<<8192, 256, 0, stream>>>(Qa, KVw, s_pos, x_pos, pw1, pb1,
                                        bn_g, bn_b, bn_m, bn_v, pw2, pb2, ObBF);
  gemm_tn_w<EPI_RES, BF, float, BF><<<512, 512, 0, stream>>>(
      ObBF, Wo_bf, bo, s, S1, 65536, 256, 256);
  ln_kernel<<<16384, 256, 0, stream>>>(S1, ln_g, ln_b, Nw);
  for (int h = 0; h < 2; ++h) {
    const size_t ro = (size_t)h * 32768;
    gemm_tn_w<EPI_GELU, BF, BF, BF><<<1024, 512, 0, stream>>>(
        Nw + ro * 256, mw1_bf, mb1, nullptr, H2, 32768, 1024, 256);
    gemm_tn<EPI_RES, BF, BF, float><<<512, 256, 0, stream>>>(
        H2, mw2_bf, mb2, S1 + ro * 256, Of + ro * 256, 32768, 256, 1024);
  }
}

// Round 16
// 381.492 us; speedup vs baseline: 1.0842x; 1.0842x over previous
//
#include <hip/hip_runtime.h>
#include <hip/hip_bf16.h>
#include <math.h>

typedef __hip_bfloat16 BF;
typedef __bf16 bf16x8 __attribute__((ext_vector_type(8)));
typedef float f32x4 __attribute__((ext_vector_type(4)));

struct alignas(8) BF4 { BF v[4]; };
struct alignas(16) BF8 { BF v[8]; };

static __device__ __forceinline__ float b2f(BF x) { return __bfloat162float(x); }
static __device__ __forceinline__ BF f2b(float x) { return __float2bfloat16(x); }

// async global->LDS, 16B per lane; LDS dest = wave-uniform base (+lane*16 implicit)
static __device__ __forceinline__ void gld_lds16(const void* g, void* l) {
  __builtin_amdgcn_global_load_lds(
      (const __attribute__((address_space(1))) unsigned int*)g,
      (__attribute__((address_space(3))) unsigned int*)l, 16, 0, 0);
}

enum { EPI_NONE = 0, EPI_RES = 1, EPI_GELU = 2 };

// ---------------------------------------------------------------------------
// One-shot prep: convert ALL weights f32->bf16 into the contiguous ws region
// (Wq|Wo|Wkv(=Wk|Wv)|mw1|mw2, 786432 elems = 196608 float4-groups) and build
// bkv. Replaces 7 tiny serialized launches with one.
// ---------------------------------------------------------------------------
__global__ void __launch_bounds__(256) cvtall_kernel(
    const float* __restrict__ Wq, const float* __restrict__ Wo,
    const float* __restrict__ Wk, const float* __restrict__ Wv,
    const float* __restrict__ mw1, const float* __restrict__ mw2,
    const float* __restrict__ bk, const float* __restrict__ bv,
    BF* __restrict__ wout, float* __restrict__ bkv) {
  const int i = blockIdx.x * 256 + threadIdx.x;   // [0, 196608)
  const float* src;
  if (i < 16384)        src = Wq  + (size_t)i * 4;
  else if (i < 32768)   src = Wo  + (size_t)(i - 16384) * 4;
  else if (i < 49152)   src = Wk  + (size_t)(i - 32768) * 4;
  else if (i < 65536)   src = Wv  + (size_t)(i - 49152) * 4;
  else if (i < 131072)  src = mw1 + (size_t)(i - 65536) * 4;
  else                  src = mw2 + (size_t)(i - 131072) * 4;
  float4 v = *(const float4*)src;
  BF4 o;
  o.v[0] = f2b(v.x); o.v[1] = f2b(v.y); o.v[2] = f2b(v.z); o.v[3] = f2b(v.w);
  ((BF4*)wout)[i] = o;
  if (i < 512) bkv[i] = (i < 256) ? bk[i] : bv[i - 256];
}

// ---------------------------------------------------------------------------
// gemm_tn: R11 form (256 threads, 128x128, LDS-coalesced epilogue, (256,4)).
// Used for Wo and MLP2 (R13-measured best for these dispatches).
// ---------------------------------------------------------------------------
template <int EPI, typename AT, typename RT, typename CT>
__global__ void __launch_bounds__(256, 4) gemm_tn(
    const AT* __restrict__ A, const BF* __restrict__ Bw,
    const float* __restrict__ bias, const RT* __restrict__ Res,
    CT* __restrict__ C, int M, int N, int K) {
  constexpr bool F32A = __is_same(AT, float);
  alignas(16) __shared__ BF smem[128 * 136];     // staging (32KB) / C-tile
  BF* As = smem;                                  // [8][128][8]
  BF* Bs = smem + 8192;                           // [8][128][8]
  BF* Cb = smem;                                  // [128][136] padded C tile
  const int ntiles = N >> 7;
  const int cpx = gridDim.x >> 3;
  const int bid = blockIdx.x;
  const int swz = (bid & 7) * cpx + (bid >> 3);   // XCD-chunked, bijective
  const int mt = swz / ntiles, nt = swz % ntiles;
  const int row0 = mt << 7, col0 = nt << 7;
  const int t = threadIdx.x;
  const int wave = t >> 6, lane = t & 63;
  const int wr = wave >> 1, wc = wave & 1;
  const int sm = t & 127;
  const int skc = t >> 7;
  f32x4 acc[4][4] = {};
  const int NT = K >> 6;
  float4 ar[4][2];

  auto stageB = [&](int kt) {
#pragma unroll
    for (int i = 0; i < 4; ++i) {
      const int kc = i * 2 + skc;
      gld_lds16(Bw + (size_t)(col0 + sm) * K + kt * 64 + kc * 8,
                Bs + (size_t)(i * 256 + wave * 64) * 8);
    }
  };
  auto loadA = [&](int kt) {
    if constexpr (F32A) {
#pragma unroll
      for (int i = 0; i < 4; ++i) {
        const int kc = i * 2 + skc;
        const float* src = A + (size_t)(row0 + sm) * K + kt * 64 + kc * 8;
        ar[i][0] = ((const float4*)src)[0];
        ar[i][1] = ((const float4*)src)[1];
      }
    }
  };
  auto writeA = [&]() {
    if constexpr (F32A) {
#pragma unroll
      for (int i = 0; i < 4; ++i) {
        const int kc = i * 2 + skc;
        BF tmp[8];
        tmp[0] = f2b(ar[i][0].x); tmp[1] = f2b(ar[i][0].y);
        tmp[2] = f2b(ar[i][0].z); tmp[3] = f2b(ar[i][0].w);
        tmp[4] = f2b(ar[i][1].x); tmp[5] = f2b(ar[i][1].y);
        tmp[6] = f2b(ar[i][1].z); tmp[7] = f2b(ar[i][1].w);
        *(bf16x8*)(As + (kc * 128 + sm) * 8) = *(bf16x8*)tmp;
      }
    }
  };
  auto stageA_bf = [&](int kt) {
    if constexpr (!F32A) {
#pragma unroll
      for (int i = 0; i < 4; ++i) {
        const int kc = i * 2 + skc;
        gld_lds16((const BF*)A + (size_t)(row0 + sm) * K + kt * 64 + kc * 8,
                  As + (size_t)(i * 256 + wave * 64) * 8);
      }
    }
  };
  auto compute = [&]() {
#pragma unroll
    for (int kk = 0; kk < 2; ++kk) {
      const int chunk = kk * 4 + (lane >> 4);
      const int rl = lane & 15;
      bf16x8 af[4], bfr[4];
#pragma unroll
      for (int mi = 0; mi < 4; ++mi)
        af[mi] = *(const bf16x8*)(As + (chunk * 128 + wr * 64 + mi * 16 + rl) * 8);
#pragma unroll
      for (int ni = 0; ni < 4; ++ni)
        bfr[ni] = *(const bf16x8*)(Bs + (chunk * 128 + wc * 64 + ni * 16 + rl) * 8);
#pragma unroll
      for (int mi = 0; mi < 4; ++mi)
#pragma unroll
        for (int ni = 0; ni < 4; ++ni)
          acc[mi][ni] = __builtin_amdgcn_mfma_f32_16x16x32_bf16(
              af[mi], bfr[ni], acc[mi][ni], 0, 0, 0);
    }
  };

  loadA(0);
  for (int kt = 0; kt < NT; ++kt) {
    writeA();
    stageA_bf(kt);
    stageB(kt);
    if (kt + 1 < NT) loadA(kt + 1);
    __syncthreads();
    compute();
    __syncthreads();
  }

  // phase 1: epi(acc+bias) -> padded LDS tile (D layout m89-verified)
  {
    const int rl = lane & 15, rg = lane >> 4;
#pragma unroll
    for (int mi = 0; mi < 4; ++mi)
#pragma unroll
      for (int ni = 0; ni < 4; ++ni) {
        const int col = wc * 64 + ni * 16 + rl;
        const float bcol = bias[col0 + col];
#pragma unroll
        for (int r = 0; r < 4; ++r) {
          const int row = wr * 64 + mi * 16 + rg * 4 + r;
          float v = acc[mi][ni][r] + bcol;
          if constexpr (EPI == EPI_GELU)
            v = 0.5f * v * (1.0f + erff(v * 0.70710678118654752f));
          Cb[row * 136 + col] = f2b(v);
        }
      }
  }
  __syncthreads();
  // phase 2: coalesced out (wave-instr = 4 complete 256B rows)
#pragma unroll
  for (int j = 0; j < 8; ++j) {
    const int row = wave * 32 + j * 4 + (lane >> 4);
    const int colc = (lane & 15) * 8;
    bf16x8 vb = *(const bf16x8*)(Cb + row * 136 + colc);
    const size_t goff = (size_t)(row0 + row) * N + col0 + colc;
    float o[8];
#pragma unroll
    for (int h = 0; h < 8; ++h) o[h] = (float)vb[h];
    if constexpr (EPI == EPI_RES) {
      if constexpr (__is_same(RT, float)) {
        float4 r0 = *(const float4*)(Res + goff);
        float4 r1 = *(const float4*)(Res + goff + 4);
        o[0] += r0.x; o[1] += r0.y; o[2] += r0.z; o[3] += r0.w;
        o[4] += r1.x; o[5] += r1.y; o[6] += r1.z; o[7] += r1.w;
      } else {
        BF8 rb = *(const BF8*)(Res + goff);
#pragma unroll
        for (int h = 0; h < 8; ++h) o[h] += b2f(rb.v[h]);
      }
    }
    if constexpr (__is_same(CT, float)) {
      float4 s0 = {o[0], o[1], o[2], o[3]};
      float4 s1 = {o[4], o[5], o[6], o[7]};
      *(float4*)(C + goff) = s0;
      *(float4*)(C + goff + 4) = s1;
    } else {
      BF8 ob;
#pragma unroll
      for (int h = 0; h < 8; ++h) ob.v[h] = f2b(o[h]);
      *(BF8*)(C + goff) = ob;
    }
  }
}

// ---------------------------------------------------------------------------
// gemm_tn_w: R12/R13-measured form. 512 threads, 128x256 tile (halves A
// re-reads), 8 waves (2x4), single 48KB LDS, m97 loop. Used ONLY for KV
// (f32 A) and MLP1 (bf16 A), where it measured 86->68us.
// ---------------------------------------------------------------------------
template <int EPI, typename AT, typename RT, typename CT>
__global__ void __launch_bounds__(512, 4) gemm_tn_w(
    const AT* __restrict__ A, const BF* __restrict__ Bw,
    const float* __restrict__ bias, const RT* __restrict__ Res,
    CT* __restrict__ C, int M, int N, int K) {
  constexpr bool F32A = __is_same(AT, float);
  alignas(16) __shared__ BF As[8][128][8];   // 16KB
  alignas(16) __shared__ BF Bs[8][256][8];   // 32KB
  const int ntiles = N >> 8;
  const int cpx = gridDim.x >> 3;
  const int bid = blockIdx.x;
  const int swz = (bid & 7) * cpx + (bid >> 3);
  const int mt = swz / ntiles, nt = swz % ntiles;
  const int row0 = mt << 7, col0 = nt << 8;
  const int t = threadIdx.x;
  const int wave = t >> 6, lane = t & 63;
  const int wr = wave >> 2, wc = wave & 3;        // 2x4 wave grid
  const int sm = t & 127;
  const int skc = t >> 7;                         // 0..3
  f32x4 acc[4][4] = {};
  const int NT = K >> 6;
  float4 ar[2][2];

  auto stageB = [&](int kt) {
#pragma unroll
    for (int i = 0; i < 4; ++i) {
      const int c = i * 512 + t;
      const int kc = c >> 8, n = c & 255;
      gld_lds16(Bw + (size_t)(col0 + n) * K + kt * 64 + kc * 8,
                &Bs[0][0][0] + (size_t)(i * 512 + wave * 64) * 8);
    }
  };
  auto stageA_bf = [&](int kt) {
    if constexpr (!F32A) {
#pragma unroll
      for (int i = 0; i < 2; ++i) {
        const int c = i * 512 + t;
        const int kc = c >> 7, m = c & 127;
        gld_lds16((const BF*)A + (size_t)(row0 + m) * K + kt * 64 + kc * 8,
                  &As[0][0][0] + (size_t)(i * 512 + wave * 64) * 8);
      }
    }
  };
  auto loadA = [&](int kt) {
    if constexpr (F32A) {
#pragma unroll
      for (int i = 0; i < 2; ++i) {
        const int kc = i * 4 + skc;
        const float* src = A + (size_t)(row0 + sm) * K + kt * 64 + kc * 8;
        ar[i][0] = ((const float4*)src)[0];
        ar[i][1] = ((const float4*)src)[1];
      }
    }
  };
  auto writeA = [&]() {
    if constexpr (F32A) {
#pragma unroll
      for (int i = 0; i < 2; ++i) {
        const int kc = i * 4 + skc;
        BF tmp[8];
        tmp[0] = f2b(ar[i][0].x); tmp[1] = f2b(ar[i][0].y);
        tmp[2] = f2b(ar[i][0].z); tmp[3] = f2b(ar[i][0].w);
        tmp[4] = f2b(ar[i][1].x); tmp[5] = f2b(ar[i][1].y);
        tmp[6] = f2b(ar[i][1].z); tmp[7] = f2b(ar[i][1].w);
        *(bf16x8*)(&As[kc][sm][0]) = *(bf16x8*)tmp;
      }
    }
  };
  auto compute = [&]() {
#pragma unroll
    for (int kk = 0; kk < 2; ++kk) {
      const int chunk = kk * 4 + (lane >> 4);
      const int rl = lane & 15;
      bf16x8 af[4], bfr[4];
#pragma unroll
      for (int mi = 0; mi < 4; ++mi)
        af[mi] = *(const bf16x8*)(&As[chunk][wr * 64 + mi * 16 + rl][0]);
#pragma unroll
      for (int ni = 0; ni < 4; ++ni)
        bfr[ni] = *(const bf16x8*)(&Bs[chunk][wc * 64 + ni * 16 + rl][0]);
#pragma unroll
      for (int mi = 0; mi < 4; ++mi)
#pragma unroll
        for (int ni = 0; ni < 4; ++ni)
          acc[mi][ni] = __builtin_amdgcn_mfma_f32_16x16x32_bf16(
              af[mi], bfr[ni], acc[mi][ni], 0, 0, 0);
    }
  };

  loadA(0);
  for (int kt = 0; kt < NT; ++kt) {
    writeA();
    stageA_bf(kt);
    stageB(kt);
    if (kt + 1 < NT) loadA(kt + 1);
    __syncthreads();
    compute();
    __syncthreads();
  }

  const int rl = lane & 15, rg = lane >> 4;
#pragma unroll
  for (int mi = 0; mi < 4; ++mi) {
#pragma unroll
    for (int ni = 0; ni < 4; ++ni) {
      const int col = col0 + wc * 64 + ni * 16 + rl;
      const float bcol = bias[col];
#pragma unroll
      for (int r = 0; r < 4; ++r) {
        const int row = row0 + wr * 64 + mi * 16 + rg * 4 + r;
        float v = acc[mi][ni][r] + bcol;
        if constexpr (EPI == EPI_GELU)
          v = 0.5f * v * (1.0f + erff(v * 0.70710678118654752f));
        if constexpr (EPI == EPI_RES) {
          if constexpr (__is_same(RT, float))
            v += Res[(size_t)row * N + col];
          else
            v += b2f(Res[(size_t)row * N + col]);
        }
        if constexpr (__is_same(CT, float))
          C[(size_t)row * N + col] = v;
        else
          C[(size_t)row * N + col] = f2b(v);
      }
    }
  }
}

// ---------------------------------------------------------------------------
// Q-projection GEMM (R11/R13 form): 256 threads, 128x128, attention-layout
// scatter epilogue (pre-scaled):
//   Qa[b][wi][nh][qi][hd] = (s @ Wq^T + bq)[b, l, c] * SCALE
// ---------------------------------------------------------------------------
__global__ void __launch_bounds__(256, 4) gemm_q(
    const float* __restrict__ A, const BF* __restrict__ Bw,
    const float* __restrict__ bias, BF* __restrict__ Qa) {
  constexpr int K = 256;
  alignas(16) __shared__ BF As[8][128][8];
  alignas(16) __shared__ BF Bs[8][128][8];
  const int cpx = gridDim.x >> 3;
  const int bid = blockIdx.x;
  const int swz = (bid & 7) * cpx + (bid >> 3);
  const int mt = swz >> 1, nt = swz & 1;
  const int hp = mt & 3, qi = (mt >> 2) & 3, nh = (mt >> 4) & 7, bb = mt >> 7;
  const int col0 = nt << 7;
  const int t = threadIdx.x;
  const int wave = t >> 6, lane = t & 63;
  const int wr = wave >> 1, wc = wave & 1;
  const int sm = t & 127;
  const int skc = t >> 7;
  const size_t grow = (size_t)bb * 16384 + nh * 2048 + (size_t)(sm & 31) * 64 +
                      qi * 16 + hp * 4 + (sm >> 5);
  f32x4 acc[4][4] = {};
  float4 ar[4][2];

  auto stageB = [&](int kt) {
#pragma unroll
    for (int i = 0; i < 4; ++i) {
      const int kc = i * 2 + skc;
      gld_lds16(Bw + (size_t)(col0 + sm) * K + kt * 64 + kc * 8,
                &Bs[0][0][0] + (size_t)(i * 256 + wave * 64) * 8);
    }
  };
  auto loadA = [&](int kt) {
#pragma unroll
    for (int i = 0; i < 4; ++i) {
      const int kc = i * 2 + skc;
      const float* src = A + grow * K + kt * 64 + kc * 8;
      ar[i][0] = ((const float4*)src)[0];
      ar[i][1] = ((const float4*)src)[1];
    }
  };
  auto writeA = [&]() {
#pragma unroll
    for (int i = 0; i < 4; ++i) {
      const int kc = i * 2 + skc;
      BF tmp[8];
      tmp[0] = f2b(ar[i][0].x); tmp[1] = f2b(ar[i][0].y);
      tmp[2] = f2b(ar[i][0].z); tmp[3] = f2b(ar[i][0].w);
      tmp[4] = f2b(ar[i][1].x); tmp[5] = f2b(ar[i][1].y);
      tmp[6] = f2b(ar[i][1].z); tmp[7] = f2b(ar[i][1].w);
      *(bf16x8*)(&As[kc][sm][0]) = *(bf16x8*)tmp;
    }
  };
  auto compute = [&]() {
#pragma unroll
    for (int kk = 0; kk < 2; ++kk) {
      const int chunk = kk * 4 + (lane >> 4);
      const int rl = lane & 15;
      bf16x8 af[4], bfr[4];
#pragma unroll
      for (int mi = 0; mi < 4; ++mi)
        af[mi] = *(const bf16x8*)(&As[chunk][wr * 64 + mi * 16 + rl][0]);
#pragma unroll
      for (int ni = 0; ni < 4; ++ni)
        bfr[ni] = *(const bf16x8*)(&Bs[chunk][wc * 64 + ni * 16 + rl][0]);
#pragma unroll
      for (int mi = 0; mi < 4; ++mi)
#pragma unroll
        for (int ni = 0; ni < 4; ++ni)
          acc[mi][ni] = __builtin_amdgcn_mfma_f32_16x16x32_bf16(
              af[mi], bfr[ni], acc[mi][ni], 0, 0, 0);
    }
  };

  loadA(0);
  for (int kt = 0; kt < 4; ++kt) {
    writeA();
    stageB(kt);
    if (kt + 1 < 4) loadA(kt + 1);
    __syncthreads();
    compute();
    __syncthreads();
  }

  const int rl = lane & 15, rg = lane >> 4;
  const float SCALE = 0.17677669529663689f;  // 32^-0.5
#pragma unroll
  for (int mi = 0; mi < 4; ++mi) {
#pragma unroll
    for (int ni = 0; ni < 4; ++ni) {
      const int col = col0 + wc * 64 + ni * 16 + rl;
      const float bcol = bias[col];
      const int i0 = wr * 64 + mi * 16 + rg * 4;
      const int hd = i0 & 31, hil = i0 >> 5;
      const int wi = (hp * 4 + hil) * 256 + col;
      BF4 pk;
#pragma unroll
      for (int r = 0; r < 4; ++r)
        pk.v[r] = f2b((acc[mi][ni][r] + bcol) * SCALE);
      *(BF4*)(Qa + ((((size_t)bb * 4096 + wi) * 8 + nh) * 128 + qi * 32 + hd)) = pk;
    }
  }
}

// ---------------------------------------------------------------------------
// Windowed attention v4 (R10/R11-verified): inline rel-bias, no LDS, no QK
// shuffles. 16-lane group per (w,nh), lane = qi*4+kj.
// ---------------------------------------------------------------------------
__global__ void __launch_bounds__(256) attn_kernel(
    const BF* __restrict__ Qa, const BF* __restrict__ KV,
    const float* __restrict__ s_pos, const float* __restrict__ x_pos,
    const float* __restrict__ pw1, const float* __restrict__ pb1,
    const float* __restrict__ bn_g, const float* __restrict__ bn_b,
    const float* __restrict__ bn_m, const float* __restrict__ bn_v,
    const float* __restrict__ pw2, const float* __restrict__ pb2,
    BF* __restrict__ O) {
  const int t = threadIdx.x;
  const int g = t >> 4, l16 = t & 15;
  const int qi = l16 >> 2, kj = l16 & 3;
  const int w = (blockIdx.x << 1) | (g >> 3);
  const int nh = g & 7;
  const int b = w >> 12, wi = w & 4095;

  const uint4* qp = (const uint4*)(Qa + ((((size_t)b * 4096 + wi) * 8 + nh) * 128 + qi * 32));
  uint4 qv[4] = {qp[0], qp[1], qp[2], qp[3]};
  const uint4* kp = (const uint4*)(KV + ((size_t)b * 16384 + kj * 4096 + wi) * 512 + nh * 32);
  uint4 kv[4] = {kp[0], kp[1], kp[2], kp[3]};
  const BF* vbase = KV + (size_t)b * 16384 * 512 + 256 + nh * 32 + kj * 8;
  uint4 vv[4];
#pragma unroll
  for (int d = 0; d < 4; ++d)
    vv[d] = *(const uint4*)(vbase + ((size_t)((kj ^ d) * 4096 + wi)) * 512);

  const size_t sprow = ((size_t)(b * 2 + (qi & 1)) * 4096 + wi) * 4;
  const float r0 = s_pos[sprow + (qi >> 1)] -
                   x_pos[((size_t)b * 16384 + kj * 4096 + wi) * 2 + 0];
  const float r1 = s_pos[sprow + 2 + (qi >> 1)] -
                   x_pos[((size_t)b * 16384 + kj * 4096 + wi) * 2 + 1];
  float bias_l = pb2[nh];
#pragma unroll
  for (int o = 0; o < 16; ++o) {
    float tv = pw1[o * 2 + 0] * r0 + pw1[o * 2 + 1] * r1 + pb1[o];
    const float sc = bn_g[o] / sqrtf(bn_v[o] + 1e-5f);
    tv = (tv - bn_m[o]) * sc + bn_b[o];
    bias_l += pw2[nh * 16 + o] * fmaxf(tv, 0.0f);
  }

  float accs[4] = {0.f, 0.f, 0.f, 0.f};
#pragma unroll
  for (int j = 0; j < 4; ++j) {
#pragma unroll
    for (int e = 0; e < 4; ++e) {
      unsigned qe = ((const unsigned*)&qv[j])[e];
      unsigned ke = ((const unsigned*)&kv[j])[e];
      float ql = __uint_as_float(qe << 16);
      float qh = __uint_as_float(qe & 0xffff0000u);
      float kl = __uint_as_float(ke << 16);
      float kh = __uint_as_float(ke & 0xffff0000u);
      accs[e] = fmaf(ql, kl, accs[e]);
      accs[e] = fmaf(qh, kh, accs[e]);
    }
  }
  const float score = accs[0] + accs[1] + accs[2] + accs[3] + bias_l;

  float mx = fmaxf(score, __shfl_xor(score, 1));
  mx = fmaxf(mx, __shfl_xor(mx, 2));
  float e = __expf(score - mx);
  float sm = e + __shfl_xor(e, 1);
  sm += __shfl_xor(sm, 2);
  float p = e / sm;
  float pd[4];
  pd[0] = p;
  pd[1] = __shfl_xor(p, 1);
  pd[2] = __shfl_xor(p, 2);
  pd[3] = __shfl_xor(pd[1], 2);

  float o8[8] = {0.f, 0.f, 0.f, 0.f, 0.f, 0.f, 0.f, 0.f};
#pragma unroll
  for (int d = 0; d < 4; ++d) {
#pragma unroll
    for (int e2 = 0; e2 < 4; ++e2) {
      unsigned ve = ((const unsigned*)&vv[d])[e2];
      o8[e2 * 2 + 0] = fmaf(pd[d], __uint_as_float(ve << 16), o8[e2 * 2 + 0]);
      o8[e2 * 2 + 1] = fmaf(pd[d], __uint_as_float(ve & 0xffff0000u), o8[e2 * 2 + 1]);
    }
  }
  BF8 ob;
#pragma unroll
  for (int h = 0; h < 8; ++h) ob.v[h] = f2b(o8[h]);
  *(BF8*)(O + ((size_t)b * 16384 + qi * 4096 + wi) * 256 + nh * 32 + kj * 8) = ob;
}

// ---------------------------------------------------------------------------
// LayerNorm over C=256: one 64-lane wave per row, 4 bf16 per lane.
// ---------------------------------------------------------------------------
__global__ void __launch_bounds__(256) ln_kernel(
    const BF* __restrict__ S1, const float* __restrict__ g,
    const float* __restrict__ be, BF* __restrict__ Nout) {
  const int wave = threadIdx.x >> 6, lane = threadIdx.x & 63;
  const size_t row = (size_t)blockIdx.x * 4 + wave;
  BF4 d = *(const BF4*)(S1 + row * 256 + lane * 4);
  float x[4] = {b2f(d.v[0]), b2f(d.v[1]), b2f(d.v[2]), b2f(d.v[3])};
  float s = x[0] + x[1] + x[2] + x[3];
  float sq = x[0] * x[0] + x[1] * x[1] + x[2] * x[2] + x[3] * x[3];
#pragma unroll
  for (int m = 1; m <= 32; m <<= 1) {
    s += __shfl_xor(s, m);
    sq += __shfl_xor(sq, m);
  }
  const float mean = s * 0.00390625f;
  const float var = sq * 0.00390625f - mean * mean;
  const float rstd = 1.0f / sqrtf(var + 1e-5f);
  BF4 o;
#pragma unroll
  for (int jj = 0; jj < 4; ++jj) {
    float nv = (x[jj] - mean) * rstd * g[lane * 4 + jj] + be[lane * 4 + jj];
    o.v[jj] = f2b(nv);
  }
  *(BF4*)(Nout + row * 256 + lane * 4) = o;
}

// ---------------------------------------------------------------------------
// ws layout (bytes): unchanged from R11-R14.
//   [8388608,    41943040)  Qa bf16 -> LN out after attn
//   [41943040,  109051904)  KV512 bf16 -> H2 after attn
//   [109051904, 142606336)  S1 bf16
//   [142606336, ~144.2MB)   bf16 weights Wq|Wo|Wkv|mw1|mw2 (contiguous); bkv f32
// d_out doubles as bf16 attn-output staging. 10 dispatches.
// ---------------------------------------------------------------------------
extern "C" void kernel_launch(void* const* d_in, const int* in_sizes, int n_in,
                              void* d_out, int out_size, void* d_ws, size_t ws_size,
                              hipStream_t stream) {
  const float* s     = (const float*)d_in[0];
  const float* x     = (const float*)d_in[1];
  const float* s_pos = (const float*)d_in[2];
  const float* x_pos = (const float*)d_in[3];
  const float* Wq = (const float*)d_in[4];  const float* bq = (const float*)d_in[5];
  const float* Wk = (const float*)d_in[6];  const float* bk = (const float*)d_in[7];
  const float* Wv = (const float*)d_in[8];  const float* bv = (const float*)d_in[9];
  const float* Wo = (const float*)d_in[10]; const float* bo = (const float*)d_in[11];
  const float* pw1 = (const float*)d_in[12]; const float* pb1 = (const float*)d_in[13];
  const float* bn_g = (const float*)d_in[14]; const float* bn_b = (const float*)d_in[15];
  const float* bn_m = (const float*)d_in[16]; const float* bn_v = (const float*)d_in[17];
  const float* pw2 = (const float*)d_in[18]; const float* pb2 = (const float*)d_in[19];
  const float* ln_g = (const float*)d_in[20]; const float* ln_b = (const float*)d_in[21];
  const float* mw1 = (const float*)d_in[22]; const float* mb1 = (const float*)d_in[23];
  const float* mw2 = (const float*)d_in[24]; const float* mb2 = (const float*)d_in[25];

  char* ws = (char*)d_ws;
  BF* Qa   = (BF*)(ws + 8388608);
  BF* KVw  = (BF*)(ws + 41943040);
  BF* S1   = (BF*)(ws + 109051904);
  BF* Wq_bf  = (BF*)(ws + 142606336);
  BF* Wo_bf  = (BF*)(ws + 142737408);
  BF* Wkv_bf = (BF*)(ws + 142868480);
  BF* mw1_bf = (BF*)(ws + 143130624);
  BF* mw2_bf = (BF*)(ws + 143654912);
  float* bkv = (float*)(ws + 144179200);
  BF* Nw = Qa;            // LN output reuses Qa region (free after attn)
  BF* H2 = KVw;           // MLP hidden reuses KV region (free after attn)
  BF* ObBF = (BF*)d_out;  // attn output staged bf16 inside d_out
  float* Of = (float*)d_out;

  cvtall_kernel<<<768, 256, 0, stream>>>(Wq, Wo, Wk, Wv, mw1, mw2, bk, bv,
                                         Wq_bf, bkv);

  gemm_q<<<1024, 256, 0, stream>>>(s, Wq_bf, bq, Qa);
  gemm_tn_w<EPI_NONE, float, float, BF><<<1024, 512, 0, stream>>>(
      x, Wkv_bf, bkv, nullptr, KVw, 65536, 512, 256);
  attn_kernel<<<8192, 256, 0, stream>>>(Qa, KVw, s_pos, x_pos, pw1, pb1,
                                        bn_g, bn_b, bn_m, bn_v, pw2, pb2, ObBF);
  gemm_tn<EPI_RES, BF, float, BF><<<1024, 256, 0, stream>>>(
      ObBF, Wo_bf, bo, s, S1, 65536, 256, 256);
  ln_kernel<<<16384, 256, 0, stream>>>(S1, ln_g, ln_b, Nw);
  for (int h = 0; h < 2; ++h) {
    const size_t ro = (size_t)h * 32768;
    gemm_tn_w<EPI_GELU, BF, BF, BF><<<1024, 512, 0, stream>>>(
        Nw + ro * 256, mw1_bf, mb1, nullptr, H2, 32768, 1024, 256);
    gemm_tn<EPI_RES, BF, BF, float><<<512, 256, 0, stream>>>(
        H2, mw2_bf, mb2, S1 + ro * 256, Of + ro * 256, 32768, 256, 1024);
  }
}

// Round 17
// 378.692 us; speedup vs baseline: 1.0922x; 1.0074x over previous
//
#include <hip/hip_runtime.h>
#include <hip/hip_bf16.h>
#include <math.h>

typedef __hip_bfloat16 BF;
typedef __bf16 bf16x8 __attribute__((ext_vector_type(8)));
typedef float f32x4 __attribute__((ext_vector_type(4)));

struct alignas(8) BF4 { BF v[4]; };
struct alignas(16) BF8 { BF v[8]; };

static __device__ __forceinline__ float b2f(BF x) { return __bfloat162float(x); }
static __device__ __forceinline__ BF f2b(float x) { return __float2bfloat16(x); }

// async global->LDS, 16B per lane; LDS dest = wave-uniform base (+lane*16 implicit)
static __device__ __forceinline__ void gld_lds16(const void* g, void* l) {
  __builtin_amdgcn_global_load_lds(
      (const __attribute__((address_space(1))) unsigned int*)g,
      (__attribute__((address_space(3))) unsigned int*)l, 16, 0, 0);
}

enum { EPI_NONE = 0, EPI_RES = 1, EPI_GELU = 2 };

// ---------------------------------------------------------------------------
// One-shot prep: convert ALL weights f32->bf16 into the contiguous ws region
// (Wq|Wo|Wkv(=Wk|Wv)|mw1|mw2) and build bkv. One launch (R15-verified).
// ---------------------------------------------------------------------------
__global__ void __launch_bounds__(256) cvtall_kernel(
    const float* __restrict__ Wq, const float* __restrict__ Wo,
    const float* __restrict__ Wk, const float* __restrict__ Wv,
    const float* __restrict__ mw1, const float* __restrict__ mw2,
    const float* __restrict__ bk, const float* __restrict__ bv,
    BF* __restrict__ wout, float* __restrict__ bkv) {
  const int i = blockIdx.x * 256 + threadIdx.x;   // [0, 196608)
  const float* src;
  if (i < 16384)        src = Wq  + (size_t)i * 4;
  else if (i < 32768)   src = Wo  + (size_t)(i - 16384) * 4;
  else if (i < 49152)   src = Wk  + (size_t)(i - 32768) * 4;
  else if (i < 65536)   src = Wv  + (size_t)(i - 49152) * 4;
  else if (i < 131072)  src = mw1 + (size_t)(i - 65536) * 4;
  else                  src = mw2 + (size_t)(i - 131072) * 4;
  float4 v = *(const float4*)src;
  BF4 o;
  o.v[0] = f2b(v.x); o.v[1] = f2b(v.y); o.v[2] = f2b(v.z); o.v[3] = f2b(v.w);
  ((BF4*)wout)[i] = o;
  if (i < 512) bkv[i] = (i < 256) ? bk[i] : bv[i - 256];
}

// ---------------------------------------------------------------------------
// gemm_tn: R11/R13 form (256 threads, 128x128, LDS-coalesced epilogue).
// Used for Wo and MLP2 (measured best for these dispatches).
// ---------------------------------------------------------------------------
template <int EPI, typename AT, typename RT, typename CT>
__global__ void __launch_bounds__(256, 4) gemm_tn(
    const AT* __restrict__ A, const BF* __restrict__ Bw,
    const float* __restrict__ bias, const RT* __restrict__ Res,
    CT* __restrict__ C, int M, int N, int K) {
  constexpr bool F32A = __is_same(AT, float);
  alignas(16) __shared__ BF smem[128 * 136];     // staging (32KB) / C-tile
  BF* As = smem;                                  // [8][128][8]
  BF* Bs = smem + 8192;                           // [8][128][8]
  BF* Cb = smem;                                  // [128][136] padded C tile
  const int ntiles = N >> 7;
  const int cpx = gridDim.x >> 3;
  const int bid = blockIdx.x;
  const int swz = (bid & 7) * cpx + (bid >> 3);   // XCD-chunked, bijective
  const int mt = swz / ntiles, nt = swz % ntiles;
  const int row0 = mt << 7, col0 = nt << 7;
  const int t = threadIdx.x;
  const int wave = t >> 6, lane = t & 63;
  const int wr = wave >> 1, wc = wave & 1;
  const int sm = t & 127;
  const int skc = t >> 7;
  f32x4 acc[4][4] = {};
  const int NT = K >> 6;
  float4 ar[4][2];

  auto stageB = [&](int kt) {
#pragma unroll
    for (int i = 0; i < 4; ++i) {
      const int kc = i * 2 + skc;
      gld_lds16(Bw + (size_t)(col0 + sm) * K + kt * 64 + kc * 8,
                Bs + (size_t)(i * 256 + wave * 64) * 8);
    }
  };
  auto loadA = [&](int kt) {
    if constexpr (F32A) {
#pragma unroll
      for (int i = 0; i < 4; ++i) {
        const int kc = i * 2 + skc;
        const float* src = A + (size_t)(row0 + sm) * K + kt * 64 + kc * 8;
        ar[i][0] = ((const float4*)src)[0];
        ar[i][1] = ((const float4*)src)[1];
      }
    }
  };
  auto writeA = [&]() {
    if constexpr (F32A) {
#pragma unroll
      for (int i = 0; i < 4; ++i) {
        const int kc = i * 2 + skc;
        BF tmp[8];
        tmp[0] = f2b(ar[i][0].x); tmp[1] = f2b(ar[i][0].y);
        tmp[2] = f2b(ar[i][0].z); tmp[3] = f2b(ar[i][0].w);
        tmp[4] = f2b(ar[i][1].x); tmp[5] = f2b(ar[i][1].y);
        tmp[6] = f2b(ar[i][1].z); tmp[7] = f2b(ar[i][1].w);
        *(bf16x8*)(As + (kc * 128 + sm) * 8) = *(bf16x8*)tmp;
      }
    }
  };
  auto stageA_bf = [&](int kt) {
    if constexpr (!F32A) {
#pragma unroll
      for (int i = 0; i < 4; ++i) {
        const int kc = i * 2 + skc;
        gld_lds16((const BF*)A + (size_t)(row0 + sm) * K + kt * 64 + kc * 8,
                  As + (size_t)(i * 256 + wave * 64) * 8);
      }
    }
  };
  auto compute = [&]() {
#pragma unroll
    for (int kk = 0; kk < 2; ++kk) {
      const int chunk = kk * 4 + (lane >> 4);
      const int rl = lane & 15;
      bf16x8 af[4], bfr[4];
#pragma unroll
      for (int mi = 0; mi < 4; ++mi)
        af[mi] = *(const bf16x8*)(As + (chunk * 128 + wr * 64 + mi * 16 + rl) * 8);
#pragma unroll
      for (int ni = 0; ni < 4; ++ni)
        bfr[ni] = *(const bf16x8*)(Bs + (chunk * 128 + wc * 64 + ni * 16 + rl) * 8);
#pragma unroll
      for (int mi = 0; mi < 4; ++mi)
#pragma unroll
        for (int ni = 0; ni < 4; ++ni)
          acc[mi][ni] = __builtin_amdgcn_mfma_f32_16x16x32_bf16(
              af[mi], bfr[ni], acc[mi][ni], 0, 0, 0);
    }
  };

  loadA(0);
  for (int kt = 0; kt < NT; ++kt) {
    writeA();
    stageA_bf(kt);
    stageB(kt);
    if (kt + 1 < NT) loadA(kt + 1);
    __syncthreads();
    compute();
    __syncthreads();
  }

  // phase 1: epi(acc+bias) -> padded LDS tile (D layout m89-verified)
  {
    const int rl = lane & 15, rg = lane >> 4;
#pragma unroll
    for (int mi = 0; mi < 4; ++mi)
#pragma unroll
      for (int ni = 0; ni < 4; ++ni) {
        const int col = wc * 64 + ni * 16 + rl;
        const float bcol = bias[col0 + col];
#pragma unroll
        for (int r = 0; r < 4; ++r) {
          const int row = wr * 64 + mi * 16 + rg * 4 + r;
          float v = acc[mi][ni][r] + bcol;
          if constexpr (EPI == EPI_GELU)
            v = 0.5f * v * (1.0f + erff(v * 0.70710678118654752f));
          Cb[row * 136 + col] = f2b(v);
        }
      }
  }
  __syncthreads();
  // phase 2: coalesced out (wave-instr = 4 complete 256B rows)
#pragma unroll
  for (int j = 0; j < 8; ++j) {
    const int row = wave * 32 + j * 4 + (lane >> 4);
    const int colc = (lane & 15) * 8;
    bf16x8 vb = *(const bf16x8*)(Cb + row * 136 + colc);
    const size_t goff = (size_t)(row0 + row) * N + col0 + colc;
    float o[8];
#pragma unroll
    for (int h = 0; h < 8; ++h) o[h] = (float)vb[h];
    if constexpr (EPI == EPI_RES) {
      if constexpr (__is_same(RT, float)) {
        float4 r0 = *(const float4*)(Res + goff);
        float4 r1 = *(const float4*)(Res + goff + 4);
        o[0] += r0.x; o[1] += r0.y; o[2] += r0.z; o[3] += r0.w;
        o[4] += r1.x; o[5] += r1.y; o[6] += r1.z; o[7] += r1.w;
      } else {
        BF8 rb = *(const BF8*)(Res + goff);
#pragma unroll
        for (int h = 0; h < 8; ++h) o[h] += b2f(rb.v[h]);
      }
    }
    if constexpr (__is_same(CT, float)) {
      float4 s0 = {o[0], o[1], o[2], o[3]};
      float4 s1 = {o[4], o[5], o[6], o[7]};
      *(float4*)(C + goff) = s0;
      *(float4*)(C + goff + 4) = s1;
    } else {
      BF8 ob;
#pragma unroll
      for (int h = 0; h < 8; ++h) ob.v[h] = f2b(o[h]);
      *(BF8*)(C + goff) = ob;
    }
  }
}

// ---------------------------------------------------------------------------
// gemm_tn_x: 1024 threads, 128x512 tile — A re-reads eliminated (KV ntiles=1)
// or halved vs R13 (MLP1 ntiles=2). 16 waves (2x8); per-wave compute is the
// IDENTICAL verified 64x64/acc[4][4] math. LDS: A 16KB + B 64KB = 80KB ->
// 2 blocks/CU. Same m97 2-barrier loop and staging patterns as gemm_tn_w.
// ---------------------------------------------------------------------------
template <int EPI, typename AT, typename RT, typename CT>
__global__ void __launch_bounds__(1024, 4) gemm_tn_x(
    const AT* __restrict__ A, const BF* __restrict__ Bw,
    const float* __restrict__ bias, const RT* __restrict__ Res,
    CT* __restrict__ C, int M, int N, int K) {
  constexpr bool F32A = __is_same(AT, float);
  alignas(16) __shared__ BF As[8][128][8];   // 16KB
  alignas(16) __shared__ BF Bs[8][512][8];   // 64KB
  const int ntiles = N >> 9;
  const int cpx = gridDim.x >> 3;
  const int bid = blockIdx.x;
  const int swz = (bid & 7) * cpx + (bid >> 3);   // XCD-chunked, bijective
  const int mt = swz / ntiles, nt = swz % ntiles;
  const int row0 = mt << 7, col0 = nt << 9;
  const int t = threadIdx.x;
  const int wave = t >> 6, lane = t & 63;
  const int wr = wave >> 3, wc = wave & 7;        // 2x8 wave grid
  const int am = t & 127;                         // A row (chunk map)
  const int akc = t >> 7;                         // A k-chunk (0..7)
  f32x4 acc[4][4] = {};
  const int NT = K >> 6;
  float4 ar[2];

  auto stageB = [&](int kt) {   // 4096 chunks: c = i*1024 + t; kc=c>>9, n=c&511
#pragma unroll
    for (int i = 0; i < 4; ++i) {
      const int c = i * 1024 + t;
      const int kc = c >> 9, n = c & 511;
      gld_lds16(Bw + (size_t)(col0 + n) * K + kt * 64 + kc * 8,
                &Bs[0][0][0] + (size_t)(i * 1024 + wave * 64) * 8);
    }
  };
  auto stageA_bf = [&](int kt) {  // 1024 chunks: c = t; kc=t>>7, m=t&127
    if constexpr (!F32A) {
      gld_lds16((const BF*)A + (size_t)(row0 + am) * K + kt * 64 + akc * 8,
                &As[0][0][0] + (size_t)(wave * 64) * 8);
    }
  };
  auto loadA = [&](int kt) {      // f32: 1 bf16x8-chunk per thread
    if constexpr (F32A) {
      const float* src = A + (size_t)(row0 + am) * K + kt * 64 + akc * 8;
      ar[0] = ((const float4*)src)[0];
      ar[1] = ((const float4*)src)[1];
    }
  };
  auto writeA = [&]() {
    if constexpr (F32A) {
      BF tmp[8];
      tmp[0] = f2b(ar[0].x); tmp[1] = f2b(ar[0].y);
      tmp[2] = f2b(ar[0].z); tmp[3] = f2b(ar[0].w);
      tmp[4] = f2b(ar[1].x); tmp[5] = f2b(ar[1].y);
      tmp[6] = f2b(ar[1].z); tmp[7] = f2b(ar[1].w);
      *(bf16x8*)(&As[akc][am][0]) = *(bf16x8*)tmp;
    }
  };
  auto compute = [&]() {
#pragma unroll
    for (int kk = 0; kk < 2; ++kk) {
      const int chunk = kk * 4 + (lane >> 4);
      const int rl = lane & 15;
      bf16x8 af[4], bfr[4];
#pragma unroll
      for (int mi = 0; mi < 4; ++mi)
        af[mi] = *(const bf16x8*)(&As[chunk][wr * 64 + mi * 16 + rl][0]);
#pragma unroll
      for (int ni = 0; ni < 4; ++ni)
        bfr[ni] = *(const bf16x8*)(&Bs[chunk][wc * 64 + ni * 16 + rl][0]);
#pragma unroll
      for (int mi = 0; mi < 4; ++mi)
#pragma unroll
        for (int ni = 0; ni < 4; ++ni)
          acc[mi][ni] = __builtin_amdgcn_mfma_f32_16x16x32_bf16(
              af[mi], bfr[ni], acc[mi][ni], 0, 0, 0);
    }
  };

  loadA(0);
  for (int kt = 0; kt < NT; ++kt) {
    writeA();
    stageA_bf(kt);
    stageB(kt);
    if (kt + 1 < NT) loadA(kt + 1);
    __syncthreads();
    compute();
    __syncthreads();
  }

  const int rl = lane & 15, rg = lane >> 4;
#pragma unroll
  for (int mi = 0; mi < 4; ++mi) {
#pragma unroll
    for (int ni = 0; ni < 4; ++ni) {
      const int col = col0 + wc * 64 + ni * 16 + rl;
      const float bcol = bias[col];
#pragma unroll
      for (int r = 0; r < 4; ++r) {
        const int row = row0 + wr * 64 + mi * 16 + rg * 4 + r;
        float v = acc[mi][ni][r] + bcol;
        if constexpr (EPI == EPI_GELU)
          v = 0.5f * v * (1.0f + erff(v * 0.70710678118654752f));
        if constexpr (EPI == EPI_RES) {
          if constexpr (__is_same(RT, float))
            v += Res[(size_t)row * N + col];
          else
            v += b2f(Res[(size_t)row * N + col]);
        }
        if constexpr (__is_same(CT, float))
          C[(size_t)row * N + col] = v;
        else
          C[(size_t)row * N + col] = f2b(v);
      }
    }
  }
}

// ---------------------------------------------------------------------------
// Q-projection GEMM (R11/R13 form): 256 threads, 128x128, attention-layout
// scatter epilogue (pre-scaled):
//   Qa[b][wi][nh][qi][hd] = (s @ Wq^T + bq)[b, l, c] * SCALE
// ---------------------------------------------------------------------------
__global__ void __launch_bounds__(256, 4) gemm_q(
    const float* __restrict__ A, const BF* __restrict__ Bw,
    const float* __restrict__ bias, BF* __restrict__ Qa) {
  constexpr int K = 256;
  alignas(16) __shared__ BF As[8][128][8];
  alignas(16) __shared__ BF Bs[8][128][8];
  const int cpx = gridDim.x >> 3;
  const int bid = blockIdx.x;
  const int swz = (bid & 7) * cpx + (bid >> 3);
  const int mt = swz >> 1, nt = swz & 1;
  const int hp = mt & 3, qi = (mt >> 2) & 3, nh = (mt >> 4) & 7, bb = mt >> 7;
  const int col0 = nt << 7;
  const int t = threadIdx.x;
  const int wave = t >> 6, lane = t & 63;
  const int wr = wave >> 1, wc = wave & 1;
  const int sm = t & 127;
  const int skc = t >> 7;
  const size_t grow = (size_t)bb * 16384 + nh * 2048 + (size_t)(sm & 31) * 64 +
                      qi * 16 + hp * 4 + (sm >> 5);
  f32x4 acc[4][4] = {};
  float4 ar[4][2];

  auto stageB = [&](int kt) {
#pragma unroll
    for (int i = 0; i < 4; ++i) {
      const int kc = i * 2 + skc;
      gld_lds16(Bw + (size_t)(col0 + sm) * K + kt * 64 + kc * 8,
                &Bs[0][0][0] + (size_t)(i * 256 + wave * 64) * 8);
    }
  };
  auto loadA = [&](int kt) {
#pragma unroll
    for (int i = 0; i < 4; ++i) {
      const int kc = i * 2 + skc;
      const float* src = A + grow * K + kt * 64 + kc * 8;
      ar[i][0] = ((const float4*)src)[0];
      ar[i][1] = ((const float4*)src)[1];
    }
  };
  auto writeA = [&]() {
#pragma unroll
    for (int i = 0; i < 4; ++i) {
      const int kc = i * 2 + skc;
      BF tmp[8];
      tmp[0] = f2b(ar[i][0].x); tmp[1] = f2b(ar[i][0].y);
      tmp[2] = f2b(ar[i][0].z); tmp[3] = f2b(ar[i][0].w);
      tmp[4] = f2b(ar[i][1].x); tmp[5] = f2b(ar[i][1].y);
      tmp[6] = f2b(ar[i][1].z); tmp[7] = f2b(ar[i][1].w);
      *(bf16x8*)(&As[kc][sm][0]) = *(bf16x8*)tmp;
    }
  };
  auto compute = [&]() {
#pragma unroll
    for (int kk = 0; kk < 2; ++kk) {
      const int chunk = kk * 4 + (lane >> 4);
      const int rl = lane & 15;
      bf16x8 af[4], bfr[4];
#pragma unroll
      for (int mi = 0; mi < 4; ++mi)
        af[mi] = *(const bf16x8*)(&As[chunk][wr * 64 + mi * 16 + rl][0]);
#pragma unroll
      for (int ni = 0; ni < 4; ++ni)
        bfr[ni] = *(const bf16x8*)(&Bs[chunk][wc * 64 + ni * 16 + rl][0]);
#pragma unroll
      for (int mi = 0; mi < 4; ++mi)
#pragma unroll
        for (int ni = 0; ni < 4; ++ni)
          acc[mi][ni] = __builtin_amdgcn_mfma_f32_16x16x32_bf16(
              af[mi], bfr[ni], acc[mi][ni], 0, 0, 0);
    }
  };

  loadA(0);
  for (int kt = 0; kt < 4; ++kt) {
    writeA();
    stageB(kt);
    if (kt + 1 < 4) loadA(kt + 1);
    __syncthreads();
    compute();
    __syncthreads();
  }

  const int rl = lane & 15, rg = lane >> 4;
  const float SCALE = 0.17677669529663689f;  // 32^-0.5
#pragma unroll
  for (int mi = 0; mi < 4; ++mi) {
#pragma unroll
    for (int ni = 0; ni < 4; ++ni) {
      const int col = col0 + wc * 64 + ni * 16 + rl;
      const float bcol = bias[col];
      const int i0 = wr * 64 + mi * 16 + rg * 4;
      const int hd = i0 & 31, hil = i0 >> 5;
      const int wi = (hp * 4 + hil) * 256 + col;
      BF4 pk;
#pragma unroll
      for (int r = 0; r < 4; ++r)
        pk.v[r] = f2b((acc[mi][ni][r] + bcol) * SCALE);
      *(BF4*)(Qa + ((((size_t)bb * 4096 + wi) * 8 + nh) * 128 + qi * 32 + hd)) = pk;
    }
  }
}

// ---------------------------------------------------------------------------
// Windowed attention v4 (R10/R11-verified): inline rel-bias, no LDS, no QK
// shuffles. 16-lane group per (w,nh), lane = qi*4+kj.
// ---------------------------------------------------------------------------
__global__ void __launch_bounds__(256) attn_kernel(
    const BF* __restrict__ Qa, const BF* __restrict__ KV,
    const float* __restrict__ s_pos, const float* __restrict__ x_pos,
    const float* __restrict__ pw1, const float* __restrict__ pb1,
    const float* __restrict__ bn_g, const float* __restrict__ bn_b,
    const float* __restrict__ bn_m, const float* __restrict__ bn_v,
    const float* __restrict__ pw2, const float* __restrict__ pb2,
    BF* __restrict__ O) {
  const int t = threadIdx.x;
  const int g = t >> 4, l16 = t & 15;
  const int qi = l16 >> 2, kj = l16 & 3;
  const int w = (blockIdx.x << 1) | (g >> 3);
  const int nh = g & 7;
  const int b = w >> 12, wi = w & 4095;

  const uint4* qp = (const uint4*)(Qa + ((((size_t)b * 4096 + wi) * 8 + nh) * 128 + qi * 32));
  uint4 qv[4] = {qp[0], qp[1], qp[2], qp[3]};
  const uint4* kp = (const uint4*)(KV + ((size_t)b * 16384 + kj * 4096 + wi) * 512 + nh * 32);
  uint4 kv[4] = {kp[0], kp[1], kp[2], kp[3]};
  const BF* vbase = KV + (size_t)b * 16384 * 512 + 256 + nh * 32 + kj * 8;
  uint4 vv[4];
#pragma unroll
  for (int d = 0; d < 4; ++d)
    vv[d] = *(const uint4*)(vbase + ((size_t)((kj ^ d) * 4096 + wi)) * 512);

  const size_t sprow = ((size_t)(b * 2 + (qi & 1)) * 4096 + wi) * 4;
  const float r0 = s_pos[sprow + (qi >> 1)] -
                   x_pos[((size_t)b * 16384 + kj * 4096 + wi) * 2 + 0];
  const float r1 = s_pos[sprow + 2 + (qi >> 1)] -
                   x_pos[((size_t)b * 16384 + kj * 4096 + wi) * 2 + 1];
  float bias_l = pb2[nh];
#pragma unroll
  for (int o = 0; o < 16; ++o) {
    float tv = pw1[o * 2 + 0] * r0 + pw1[o * 2 + 1] * r1 + pb1[o];
    const float sc = bn_g[o] / sqrtf(bn_v[o] + 1e-5f);
    tv = (tv - bn_m[o]) * sc + bn_b[o];
    bias_l += pw2[nh * 16 + o] * fmaxf(tv, 0.0f);
  }

  float accs[4] = {0.f, 0.f, 0.f, 0.f};
#pragma unroll
  for (int j = 0; j < 4; ++j) {
#pragma unroll
    for (int e = 0; e < 4; ++e) {
      unsigned qe = ((const unsigned*)&qv[j])[e];
      unsigned ke = ((const unsigned*)&kv[j])[e];
      float ql = __uint_as_float(qe << 16);
      float qh = __uint_as_float(qe & 0xffff0000u);
      float kl = __uint_as_float(ke << 16);
      float kh = __uint_as_float(ke & 0xffff0000u);
      accs[e] = fmaf(ql, kl, accs[e]);
      accs[e] = fmaf(qh, kh, accs[e]);
    }
  }
  const float score = accs[0] + accs[1] + accs[2] + accs[3] + bias_l;

  float mx = fmaxf(score, __shfl_xor(score, 1));
  mx = fmaxf(mx, __shfl_xor(mx, 2));
  float e = __expf(score - mx);
  float sm = e + __shfl_xor(e, 1);
  sm += __shfl_xor(sm, 2);
  float p = e / sm;
  float pd[4];
  pd[0] = p;
  pd[1] = __shfl_xor(p, 1);
  pd[2] = __shfl_xor(p, 2);
  pd[3] = __shfl_xor(pd[1], 2);

  float o8[8] = {0.f, 0.f, 0.f, 0.f, 0.f, 0.f, 0.f, 0.f};
#pragma unroll
  for (int d = 0; d < 4; ++d) {
#pragma unroll
    for (int e2 = 0; e2 < 4; ++e2) {
      unsigned ve = ((const unsigned*)&vv[d])[e2];
      o8[e2 * 2 + 0] = fmaf(pd[d], __uint_as_float(ve << 16), o8[e2 * 2 + 0]);
      o8[e2 * 2 + 1] = fmaf(pd[d], __uint_as_float(ve & 0xffff0000u), o8[e2 * 2 + 1]);
    }
  }
  BF8 ob;
#pragma unroll
  for (int h = 0; h < 8; ++h) ob.v[h] = f2b(o8[h]);
  *(BF8*)(O + ((size_t)b * 16384 + qi * 4096 + wi) * 256 + nh * 32 + kj * 8) = ob;
}

// ---------------------------------------------------------------------------
// LayerNorm over C=256: one 64-lane wave per row, 4 bf16 per lane.
// ---------------------------------------------------------------------------
__global__ void __launch_bounds__(256) ln_kernel(
    const BF* __restrict__ S1, const float* __restrict__ g,
    const float* __restrict__ be, BF* __restrict__ Nout) {
  const int wave = threadIdx.x >> 6, lane = threadIdx.x & 63;
  const size_t row = (size_t)blockIdx.x * 4 + wave;
  BF4 d = *(const BF4*)(S1 + row * 256 + lane * 4);
  float x[4] = {b2f(d.v[0]), b2f(d.v[1]), b2f(d.v[2]), b2f(d.v[3])};
  float s = x[0] + x[1] + x[2] + x[3];
  float sq = x[0] * x[0] + x[1] * x[1] + x[2] * x[2] + x[3] * x[3];
#pragma unroll
  for (int m = 1; m <= 32; m <<= 1) {
    s += __shfl_xor(s, m);
    sq += __shfl_xor(sq, m);
  }
  const float mean = s * 0.00390625f;
  const float var = sq * 0.00390625f - mean * mean;
  const float rstd = 1.0f / sqrtf(var + 1e-5f);
  BF4 o;
#pragma unroll
  for (int jj = 0; jj < 4; ++jj) {
    float nv = (x[jj] - mean) * rstd * g[lane * 4 + jj] + be[lane * 4 + jj];
    o.v[jj] = f2b(nv);
  }
  *(BF4*)(Nout + row * 256 + lane * 4) = o;
}

// ---------------------------------------------------------------------------
// ws layout (bytes): unchanged from R11-R15.
//   [8388608,    41943040)  Qa bf16 -> LN out after attn
//   [41943040,  109051904)  KV512 bf16 -> H2 after attn
//   [109051904, 142606336)  S1 bf16
//   [142606336, ~144.2MB)   bf16 weights Wq|Wo|Wkv|mw1|mw2 (contiguous); bkv f32
// d_out doubles as bf16 attn-output staging. 10 dispatches.
// ---------------------------------------------------------------------------
extern "C" void kernel_launch(void* const* d_in, const int* in_sizes, int n_in,
                              void* d_out, int out_size, void* d_ws, size_t ws_size,
                              hipStream_t stream) {
  const float* s     = (const float*)d_in[0];
  const float* x     = (const float*)d_in[1];
  const float* s_pos = (const float*)d_in[2];
  const float* x_pos = (const float*)d_in[3];
  const float* Wq = (const float*)d_in[4];  const float* bq = (const float*)d_in[5];
  const float* Wk = (const float*)d_in[6];  const float* bk = (const float*)d_in[7];
  const float* Wv = (const float*)d_in[8];  const float* bv = (const float*)d_in[9];
  const float* Wo = (const float*)d_in[10]; const float* bo = (const float*)d_in[11];
  const float* pw1 = (const float*)d_in[12]; const float* pb1 = (const float*)d_in[13];
  const float* bn_g = (const float*)d_in[14]; const float* bn_b = (const float*)d_in[15];
  const float* bn_m = (const float*)d_in[16]; const float* bn_v = (const float*)d_in[17];
  const float* pw2 = (const float*)d_in[18]; const float* pb2 = (const float*)d_in[19];
  const float* ln_g = (const float*)d_in[20]; const float* ln_b = (const float*)d_in[21];
  const float* mw1 = (const float*)d_in[22]; const float* mb1 = (const float*)d_in[23];
  const float* mw2 = (const float*)d_in[24]; const float* mb2 = (const float*)d_in[25];

  char* ws = (char*)d_ws;
  BF* Qa   = (BF*)(ws + 8388608);
  BF* KVw  = (BF*)(ws + 41943040);
  BF* S1   = (BF*)(ws + 109051904);
  BF* Wq_bf  = (BF*)(ws + 142606336);
  BF* Wo_bf  = (BF*)(ws + 142737408);
  BF* Wkv_bf = (BF*)(ws + 142868480);
  BF* mw1_bf = (BF*)(ws + 143130624);
  BF* mw2_bf = (BF*)(ws + 143654912);
  float* bkv = (float*)(ws + 144179200);
  BF* Nw = Qa;            // LN output reuses Qa region (free after attn)
  BF* H2 = KVw;           // MLP hidden reuses KV region (free after attn)
  BF* ObBF = (BF*)d_out;  // attn output staged bf16 inside d_out
  float* Of = (float*)d_out;

  cvtall_kernel<<<768, 256, 0, stream>>>(Wq, Wo, Wk, Wv, mw1, mw2, bk, bv,
                                         Wq_bf, bkv);

  gemm_q<<<1024, 256, 0, stream>>>(s, Wq_bf, bq, Qa);
  gemm_tn_x<EPI_NONE, float, float, BF><<<512, 1024, 0, stream>>>(
      x, Wkv_bf, bkv, nullptr, KVw, 65536, 512, 256);
  attn_kernel<<<8192, 256, 0, stream>>>(Qa, KVw, s_pos, x_pos, pw1, pb1,
                                        bn_g, bn_b, bn_m, bn_v, pw2, pb2, ObBF);
  gemm_tn<EPI_RES, BF, float, BF><<<1024, 256, 0, stream>>>(
      ObBF, Wo_bf, bo, s, S1, 65536, 256, 256);
  ln_kernel<<<16384, 256, 0, stream>>>(S1, ln_g, ln_b, Nw);
  for (int h = 0; h < 2; ++h) {
    const size_t ro = (size_t)h * 32768;
    gemm_tn_x<EPI_GELU, BF, BF, BF><<<512, 1024, 0, stream>>>(
        Nw + ro * 256, mw1_bf, mb1, nullptr, H2, 32768, 1024, 256);
    gemm_tn<EPI_RES, BF, BF, float><<<512, 256, 0, stream>>>(
        H2, mw2_bf, mb2, S1 + ro * 256, Of + ro * 256, 32768, 256, 1024);
  }
}